// Round 5
// baseline (210.050 us; speedup 1.0000x reference)
//
#include <hip/hip_runtime.h>

#define STEPS 100
#define GCONST 20.0f

typedef float v2f __attribute__((ext_vector_type(2)));

// One thread advances 2 independent simulations (v2f state in registers).
// 125k threads (~7.6 waves/CU) stream y_hist and h_hist with coalesced
// 8B/lane non-temporal stores (write-once data; bypass L2 churn).
__global__ __launch_bounds__(256) void sim_scan_kernel(
    const float* __restrict__ h0,
    const float* __restrict__ pa1,
    const float* __restrict__ pa2,
    const float* __restrict__ pth,
    float* __restrict__ out,
    int n)
{
    const int nv = n >> 1;  // number of float2 groups
    const int i = blockIdx.x * blockDim.x + threadIdx.x;
    if (i >= nv) return;

    const float a1 = *pa1;
    const float a2 = *pa2;
    const float th = *pth;
    const float denom = 1.0f - a1 * (1.0f - th);

    v2f h = reinterpret_cast<const v2f*>(h0)[i];

    // d_out layout: y_hist [STEPS][n] followed by h_hist [STEPS][n]
    v2f* oy = reinterpret_cast<v2f*>(out) + i;
    v2f* oh = reinterpret_cast<v2f*>(out + (size_t)STEPS * (size_t)n) + i;

    #pragma unroll 5
    for (int t = 0; t < STEPS; ++t) {
        v2f y, yd, c;
        // y = (g + a2*h) / denom   (keep IEEE division to match reference)
        y.x = (GCONST + a2 * h.x) / denom;
        y.y = (GCONST + a2 * h.y) / denom;
        // yd = y - theta*y
        yd.x = y.x - th * y.x;
        yd.y = y.y - th * y.y;
        // c = a1*yd + a2*h
        c.x = a1 * yd.x + a2 * h.x;
        c.y = a1 * yd.y + a2 * h.y;
        // h = h + (yd - c)
        h.x = h.x + (yd.x - c.x);
        h.y = h.y + (yd.y - c.y);

        __builtin_nontemporal_store(y, oy);
        __builtin_nontemporal_store(h, oh);
        oy += nv;
        oh += nv;
    }
}

// Scalar tail kernel in case n is odd (not needed for n=250000 but safe).
__global__ void sim_scan_tail_kernel(
    const float* __restrict__ h0,
    const float* __restrict__ pa1,
    const float* __restrict__ pa2,
    const float* __restrict__ pth,
    float* __restrict__ out,
    int n, int start)
{
    int i = start + blockIdx.x * blockDim.x + threadIdx.x;
    if (i >= n) return;

    const float a1 = *pa1;
    const float a2 = *pa2;
    const float th = *pth;
    const float denom = 1.0f - a1 * (1.0f - th);

    float h = h0[i];
    float* oy = out + i;
    float* oh = out + (size_t)STEPS * (size_t)n + i;

    for (int t = 0; t < STEPS; ++t) {
        float y = (GCONST + a2 * h) / denom;
        float yd = y - th * y;
        float c = a1 * yd + a2 * h;
        h = h + (yd - c);
        *oy = y;
        *oh = h;
        oy += n;
        oh += n;
    }
}

extern "C" void kernel_launch(void* const* d_in, const int* in_sizes, int n_in,
                              void* d_out, int out_size, void* d_ws, size_t ws_size,
                              hipStream_t stream) {
    const float* h0 = (const float*)d_in[0];
    const float* a1 = (const float*)d_in[1];
    const float* a2 = (const float*)d_in[2];
    const float* th = (const float*)d_in[3];
    float* out = (float*)d_out;

    const int n = in_sizes[0];
    const int nv = n / 2;

    const int block = 256;
    const int grid = (nv + block - 1) / block;
    if (nv > 0) {
        sim_scan_kernel<<<grid, block, 0, stream>>>(h0, a1, a2, th, out, n);
    }
    const int rem_start = nv * 2;
    if (rem_start < n) {
        const int rem = n - rem_start;
        sim_scan_tail_kernel<<<(rem + 63) / 64, 64, 0, stream>>>(
            h0, a1, a2, th, out, n, rem_start);
    }
}

// Round 7
// 200.304 us; speedup vs baseline: 1.0487x; 1.0487x over previous
//
#include <hip/hip_runtime.h>

#define STEPS 100
#define GCONST 20.0f

typedef float v2f __attribute__((ext_vector_type(2)));

// One thread advances 2 independent simulations (v2f state in registers).
// 125k threads (~7.6 waves/CU) stream y_hist and h_hist with coalesced
// 8B/lane plain stores (the harness's fill kernel proves plain streaming
// stores hit 80% of HBM peak even at 9.6% occupancy; NT was the one
// untested variable vs that baseline, so it's removed).
__global__ __launch_bounds__(256) void sim_scan_kernel(
    const float* __restrict__ h0,
    const float* __restrict__ pa1,
    const float* __restrict__ pa2,
    const float* __restrict__ pth,
    float* __restrict__ out,
    int n)
{
    const int nv = n >> 1;  // number of float2 groups
    const int i = blockIdx.x * blockDim.x + threadIdx.x;
    if (i >= nv) return;

    const float a1 = *pa1;
    const float a2 = *pa2;
    const float th = *pth;
    const float denom = 1.0f - a1 * (1.0f - th);

    v2f h = reinterpret_cast<const v2f*>(h0)[i];

    // d_out layout: y_hist [STEPS][n] followed by h_hist [STEPS][n]
    v2f* oy = reinterpret_cast<v2f*>(out) + i;
    v2f* oh = reinterpret_cast<v2f*>(out + (size_t)STEPS * (size_t)n) + i;

    #pragma unroll 5
    for (int t = 0; t < STEPS; ++t) {
        v2f y, yd, c;
        // y = (g + a2*h) / denom   (keep IEEE division to match reference)
        y.x = (GCONST + a2 * h.x) / denom;
        y.y = (GCONST + a2 * h.y) / denom;
        // yd = y - theta*y
        yd.x = y.x - th * y.x;
        yd.y = y.y - th * y.y;
        // c = a1*yd + a2*h
        c.x = a1 * yd.x + a2 * h.x;
        c.y = a1 * yd.y + a2 * h.y;
        // h = h + (yd - c)
        h.x = h.x + (yd.x - c.x);
        h.y = h.y + (yd.y - c.y);

        *oy = y;
        *oh = h;
        oy += nv;
        oh += nv;
    }
}

// Scalar tail kernel in case n is odd (not needed for n=250000 but safe).
__global__ void sim_scan_tail_kernel(
    const float* __restrict__ h0,
    const float* __restrict__ pa1,
    const float* __restrict__ pa2,
    const float* __restrict__ pth,
    float* __restrict__ out,
    int n, int start)
{
    int i = start + blockIdx.x * blockDim.x + threadIdx.x;
    if (i >= n) return;

    const float a1 = *pa1;
    const float a2 = *pa2;
    const float th = *pth;
    const float denom = 1.0f - a1 * (1.0f - th);

    float h = h0[i];
    float* oy = out + i;
    float* oh = out + (size_t)STEPS * (size_t)n + i;

    for (int t = 0; t < STEPS; ++t) {
        float y = (GCONST + a2 * h) / denom;
        float yd = y - th * y;
        float c = a1 * yd + a2 * h;
        h = h + (yd - c);
        *oy = y;
        *oh = h;
        oy += n;
        oh += n;
    }
}

extern "C" void kernel_launch(void* const* d_in, const int* in_sizes, int n_in,
                              void* d_out, int out_size, void* d_ws, size_t ws_size,
                              hipStream_t stream) {
    const float* h0 = (const float*)d_in[0];
    const float* a1 = (const float*)d_in[1];
    const float* a2 = (const float*)d_in[2];
    const float* th = (const float*)d_in[3];
    float* out = (float*)d_out;

    const int n = in_sizes[0];
    const int nv = n / 2;

    const int block = 256;
    const int grid = (nv + block - 1) / block;
    if (nv > 0) {
        sim_scan_kernel<<<grid, block, 0, stream>>>(h0, a1, a2, th, out, n);
    }
    const int rem_start = nv * 2;
    if (rem_start < n) {
        const int rem = n - rem_start;
        sim_scan_tail_kernel<<<(rem + 63) / 64, 64, 0, stream>>>(
            h0, a1, a2, th, out, n, rem_start);
    }
}